// Round 9
// baseline (1486.429 us; speedup 1.0000x reference)
//
#include <hip/hip_runtime.h>
#include <hip/hip_cooperative_groups.h>
#include <cstdint>
#include <cstddef>

namespace cg = cooperative_groups;

#define NN 50000
#define NE 800000
#define NEPAD (NE + 3 * NN)   // CSR rows padded to multiple of 4
#define HID 128
#define NGRAPH 64
#define NCLASS 10
#define NREP 8
#define NBLK 3125             // 16-node blocks (50000/16 exact)
#define NFRAG (NBLK * 8)      // gemm0 fragment tiles (16 rows x 16 cols)
#define CONVB_UNITS (7 * 2048)

// 1/sqrt(1+1e-5), computed in double, rounded to f32
static constexpr float BN_INV = 0.9999950000374996f;

typedef __attribute__((ext_vector_type(8))) __bf16 bf16x8;
typedef __attribute__((ext_vector_type(4))) float floatx4;

__device__ __forceinline__ unsigned int f32_to_bf16_rne(float f) {
    unsigned int u = __float_as_uint(f);
    return (u + 0x7FFFu + ((u >> 16) & 1u)) >> 16;
}
__device__ __forceinline__ float bf16_to_f32(unsigned int h) {
    return __uint_as_float(h << 16);
}
__device__ __forceinline__ void split2(float a, float b, unsigned int& hi,
                                       unsigned int& lo) {
    unsigned int h0 = f32_to_bf16_rne(a), h1 = f32_to_bf16_rne(b);
    unsigned int l0 = f32_to_bf16_rne(a - bf16_to_f32(h0));
    unsigned int l1 = f32_to_bf16_rne(b - bf16_to_f32(h1));
    hi = h0 | (h1 << 16);
    lo = l0 | (l1 << 16);
}

// ---- SpMM phase bodies as macros (device-fn LDS form ICEs clang).
// Gather: R8-proven 1 node/wave, 512 B row bursts, scalarized packed meta.
// IT uniform across blocks; barriers unconditional; stores act-guarded.

#define SPMM_GATHER(TIN_)                                                       \
      const int node = nbs * 16 + wv;                                           \
      const int start = __builtin_amdgcn_readfirstlane(rowptr[node]);           \
      const int dg = __builtin_amdgcn_readfirstlane(degT[node]);                \
      const int cnt4 = act ? ((dg + 3) >> 2) : 0;                               \
      float4 acc = {0.f, 0.f, 0.f, 0.f};                                        \
      _Pragma("unroll 4")                                                       \
      for (int q = 0; q < cnt4; ++q) {                                          \
        const int4 m4 = *(const int4*)(meta + start + q * 4);                   \
        const unsigned int mvA = (unsigned int)(h ? m4.y : m4.x);               \
        const unsigned int mvB = (unsigned int)(h ? m4.w : m4.z);               \
        const int rowA = (int)(mvA & 0x1FFFFu);                                 \
        const int rowB = (int)(mvB & 0x1FFFFu);                                 \
        float wA = rsqrtf((float)((mvA >> 17) + 1u));                           \
        float wB = rsqrtf((float)((mvB >> 17) + 1u));                           \
        wA = ((int)mvA < 0) ? 0.f : wA;                                         \
        wB = ((int)mvB < 0) ? 0.f : wB;                                         \
        const float4 vA = *(const float4*)&TIN_[(size_t)rowA * 128 + f4 * 4];   \
        const float4 vB = *(const float4*)&TIN_[(size_t)rowB * 128 + f4 * 4];   \
        acc.x = fmaf(wA, vA.x, acc.x); acc.y = fmaf(wA, vA.y, acc.y);           \
        acc.z = fmaf(wA, vA.z, acc.z); acc.w = fmaf(wA, vA.w, acc.w);           \
        acc.x = fmaf(wB, vB.x, acc.x); acc.y = fmaf(wB, vB.y, acc.y);           \
        acc.z = fmaf(wB, vB.z, acc.z); acc.w = fmaf(wB, vB.w, acc.w);           \
      }                                                                         \
      acc.x += __shfl_xor(acc.x, 32);                                           \
      acc.y += __shfl_xor(acc.y, 32);                                           \
      acc.z += __shfl_xor(acc.z, 32);                                           \
      acc.w += __shfl_xor(acc.w, 32);                                           \
      const int f0 = f4 * 4;                                                    \
      float4 o;                                                                 \
      if (h == 0) {                                                             \
        const float di = rsqrtf((float)(dg + 1));                               \
        const float dii = di * di;                                              \
        const float4 tv = *(const float4*)&TIN_[(size_t)node * 128 + f0];       \
        const float4 bv = *(const float4*)&(BIAS_)[f0];                         \
        const float4 gv = *(const float4*)&(GAM_)[f0];                          \
        const float4 ev = *(const float4*)&(BET_)[f0];                          \
        float4 cc;                                                              \
        cc.x = di * acc.x + dii * tv.x + bv.x;                                  \
        cc.y = di * acc.y + dii * tv.y + bv.y;                                  \
        cc.z = di * acc.z + dii * tv.z + bv.z;                                  \
        cc.w = di * acc.w + dii * tv.w + bv.w;                                  \
        if (RES_) {                                                             \
          const float4 rv = *(const float4*)&(RIN_)[(size_t)node * 128 + f0];   \
          cc.x += rv.x; cc.y += rv.y; cc.z += rv.z; cc.w += rv.w;               \
        }                                                                       \
        o.x = fmaxf(cc.x * (BN_INV * gv.x) + ev.x, 0.f);                        \
        o.y = fmaxf(cc.y * (BN_INV * gv.y) + ev.y, 0.f);                        \
        o.z = fmaxf(cc.z * (BN_INV * gv.z) + ev.z, 0.f);                        \
        o.w = fmaxf(cc.w * (BN_INV * gv.w) + ev.w, 0.f);                        \
      }

#define SPMM_MID(TIN_, W1H_, W1L_, W2H_, W2L_, TOUT_, ROUT_)                    \
  {                                                                             \
    const int IT = (NBLK + G - 1) / G;                                          \
    for (int it = 0; it < IT; ++it) {                                           \
      const int nb = bid + it * G;                                              \
      const bool act = nb < NBLK;                                               \
      const int nbs = act ? nb : (NBLK - 1);                                    \
      SPMM_GATHER(TIN_)                                                         \
      if (h == 0) {                                                             \
        unsigned int H0, L0, H1, L1;                                            \
        split2(o.x, o.y, H0, L0);                                               \
        split2(o.z, o.w, H1, L1);                                               \
        const int uu0 = f4 >> 1;                                                \
        const int ro = wv ^ uu0;                                                \
        const int so = (f4 & 1) * 4;                                            \
        uint2 Hv; Hv.x = H0; Hv.y = H1;                                         \
        uint2 Lv; Lv.x = L0; Lv.y = L1;                                         \
        *(uint2*)&shU[0][uu0][ro][so] = Hv;                                     \
        *(uint2*)&shU[1][uu0][ro][so] = Lv;                                     \
      }                                                                         \
      const int mmat = (tid >> 6) >> 3;                                         \
      const int mnb = (tid >> 6) & 7;                                           \
      const unsigned short* BH_ = mmat ? (W2H_) : (W1H_);                       \
      const unsigned short* BL_ = mmat ? (W2L_) : (W1L_);                       \
      bf16x8 bHr[4], bLr[4];                                                    \
      _Pragma("unroll")                                                         \
      for (int kc = 0; kc < 4; ++kc) {                                          \
        bHr[kc] = *(const bf16x8*)(BH_ + ((size_t)mnb * 4 + kc) * 512 + lane * 8); \
        bLr[kc] = *(const bf16x8*)(BL_ + ((size_t)mnb * 4 + kc) * 512 + lane * 8); \
      }                                                                         \
      __syncthreads();                                                          \
      float* outp = mmat ? (ROUT_) : (TOUT_);                                   \
      floatx4 accG = {0.f, 0.f, 0.f, 0.f};                                      \
      _Pragma("unroll")                                                         \
      for (int kc = 0; kc < 4; ++kc) {                                          \
        const int uu = kc * 4 + (lane >> 4);                                    \
        const int rr = (lane & 15) ^ uu;                                        \
        bf16x8 aH = *(const bf16x8*)&shU[0][uu][rr][0];                         \
        bf16x8 aL = *(const bf16x8*)&shU[1][uu][rr][0];                         \
        accG = __builtin_amdgcn_mfma_f32_16x16x32_bf16(aH, bHr[kc], accG, 0, 0, 0); \
        accG = __builtin_amdgcn_mfma_f32_16x16x32_bf16(aH, bLr[kc], accG, 0, 0, 0); \
        accG = __builtin_amdgcn_mfma_f32_16x16x32_bf16(aL, bHr[kc], accG, 0, 0, 0); \
      }                                                                         \
      const int quad = lane >> 4;                                               \
      const int c0 = mnb * 16 + (lane & 15);                                    \
      const int row0 = nbs * 16 + quad * 4;                                     \
      if (act) {                                                                \
        _Pragma("unroll")                                                       \
        for (int rr2 = 0; rr2 < 4; ++rr2)                                       \
          outp[(size_t)(row0 + rr2) * 128 + c0] = accG[rr2];                    \
      }                                                                         \
      __syncthreads();                                                          \
    }                                                                           \
  }

#define SPMM_LAST(TIN_)                                                         \
  {                                                                             \
    const int IT = (NBLK + G - 1) / G;                                          \
    for (int it = 0; it < IT; ++it) {                                           \
      const int nb = bid + it * G;                                              \
      const bool act = nb < NBLK;                                               \
      const int nbs = act ? nb : (NBLK - 1);                                    \
      SPMM_GATHER(TIN_)                                                         \
      bool uni = (batch[nbs * 16] == batch[nbs * 16 + 15]);                     \
      if (uni) {                                                                \
        if (h == 0) *(float4*)&shP[wv][f0] = o;                                 \
        __syncthreads();                                                        \
        if (wv == 0 && act) {                                                   \
          float a = shP[0][2 * lane], b = shP[0][2 * lane + 1];                 \
          _Pragma("unroll")                                                     \
          for (int w2 = 1; w2 < 16; ++w2) {                                     \
            a = fmaxf(a, shP[w2][2 * lane]);                                    \
            b = fmaxf(b, shP[w2][2 * lane + 1]);                                \
          }                                                                     \
          int g2 = batch[nbs * 16];                                             \
          atomicMax((unsigned int*)&pooled[g2 * 128 + 2 * lane],                \
                    __float_as_uint(a));                                        \
          atomicMax((unsigned int*)&pooled[g2 * 128 + 2 * lane + 1],            \
                    __float_as_uint(b));                                        \
        }                                                                       \
        __syncthreads();                                                        \
      } else if (h == 0 && act) {                                               \
        int g2 = batch[node];                                                   \
        atomicMax((unsigned int*)&pooled[g2 * 128 + f0], __float_as_uint(o.x)); \
        atomicMax((unsigned int*)&pooled[g2 * 128 + f0 + 1], __float_as_uint(o.y)); \
        atomicMax((unsigned int*)&pooled[g2 * 128 + f0 + 2], __float_as_uint(o.z)); \
        atomicMax((unsigned int*)&pooled[g2 * 128 + f0 + 3], __float_as_uint(o.w)); \
      }                                                                         \
    }                                                                           \
  }

// ---------------- the mega-kernel ----------------

__global__ __launch_bounds__(1024, 8) void k_mega(
    const float* __restrict__ x, const int* __restrict__ ei,
    const int* __restrict__ batch,
    const float* __restrict__ W0, const float* __restrict__ b0,
    const float* __restrict__ g0, const float* __restrict__ be0,
    const float* __restrict__ Wh, const float* __restrict__ bh,
    const float* __restrict__ gh, const float* __restrict__ beh,
    const float* __restrict__ Rh,
    const float* __restrict__ mW1, const float* __restrict__ mb1,
    const float* __restrict__ mW2, const float* __restrict__ mb2,
    float* __restrict__ out,
    int* deg8, int* degT, int* rowptr, int* cur, int* cursor, int* meta,
    float* tA, float* tB, float* rA, float* rB,
    unsigned short* wbH, unsigned short* wbL, float* pooled) {
    cg::grid_group grid = cg::this_grid();
    __shared__ unsigned short shU[2][16][16][8];  // 8 KB: spmm staging
    __shared__ float shP[16][128];                // 8 KB: LAST pooling
    __shared__ int shSI[1024];                    // 4 KB: phase-2 scan
    __shared__ float shZ[1024];                   // 4 KB: head hidden
    __shared__ int baseS;

    const int tid = threadIdx.x;
    const int bid = blockIdx.x;
    const int G = gridDim.x;
    const int GT = G * 1024;
    const int gtid = bid * 1024 + tid;
    const int lane = tid & 63;
    const int h = lane >> 5;
    const int f4 = lane & 31;
    const int wv = __builtin_amdgcn_readfirstlane(tid >> 6);

    // ---- phase 0: zero deg8 + pooled + cursor
    for (int i = gtid; i < NREP * NN; i += GT) deg8[i] = 0;
    for (int i = gtid; i < NGRAPH * HID; i += GT) pooled[i] = 0.f;
    if (gtid == 0) cursor[0] = 0;
    __threadfence();
    grid.sync();

    // ---- phase 1: deg histogram + convB weight swizzle
    for (int w = gtid; w < NE + CONVB_UNITS; w += GT) {
        if (w < NE) {
            atomicAdd(&deg8[(w & (NREP - 1)) * NN + ei[NE + w]], 1);
        } else {
            int w2 = w - NE;
            int mat = w2 >> 11;
            int u = w2 & 2047;
            const float* src = (mat == 0) ? W0
                             : (mat <= 3) ? (Wh + (size_t)(mat - 1) * 16384)
                                          : (Rh + (size_t)(mat - 4) * 16384);
            int l2 = u & 63;
            int blk = u >> 6;
            int kblk = blk & 3;
            int nb2 = blk >> 2;
            int n = nb2 * 16 + (l2 & 15);
            int k = kblk * 32 + (l2 >> 4) * 8;
            union { unsigned int i[4]; uint4 v; } H, L;
#pragma unroll
            for (int j = 0; j < 4; ++j) {
                float a = src[(size_t)(k + 2 * j) * 128 + n];
                float c = src[(size_t)(k + 2 * j + 1) * 128 + n];
                split2(a, c, H.i[j], L.i[j]);
            }
            size_t base = (size_t)mat * 16384 + (size_t)u * 8;
            *(uint4*)&wbH[base] = H.v;
            *(uint4*)&wbL[base] = L.v;
        }
    }
    __threadfence();
    grid.sync();

    // ---- phase 2: degT + rowptr (block scan + global cursor) + pads + cur=0
    {
        const int i = gtid;          // G*1024 >= 262144 > NN: single pass
        int dsum = 0, v = 0;
        if (i < NN) {
#pragma unroll
            for (int r = 0; r < NREP; ++r) dsum += deg8[r * NN + i];
            degT[i] = dsum;
            cur[i] = 0;
            v = (dsum + 3) & ~3;
        }
        shSI[tid] = v;
        __syncthreads();
        for (int o2 = 1; o2 < 1024; o2 <<= 1) {
            int tv = (tid >= o2) ? shSI[tid - o2] : 0;
            __syncthreads();
            shSI[tid] += tv;
            __syncthreads();
        }
        const int incl = shSI[tid];
        const int total = shSI[1023];
        if (tid == 0) baseS = atomicAdd(cursor, total);
        __syncthreads();
        if (i < NN) {
            int rp = baseS + incl - v;
            rowptr[i] = rp;
            for (int p = rp + dsum; p < rp + v; ++p) meta[p] = (int)0x80000000u;
        }
    }
    __threadfence();
    grid.sync();

    // ---- phase 3: fill (blocks [0,FB)) || gemm0 fragment-waves [FB,G)
    {
        const int FB = G >> 2;
        if (bid < FB) {
            for (int e = bid * 1024 + tid; e < NE; e += FB * 1024) {
                int s = ei[e];
                int d = ei[NE + e];
                int slot = atomicAdd(&cur[d], 1);
                meta[rowptr[d] + slot] = s | (degT[s] << 17);
            }
        } else {
            const int gw = ((bid - FB) << 4) + (tid >> 6);
            const int GW = (G - FB) << 4;
            const int row16 = lane & 15;
            const int kq = lane >> 4;
            for (int f = gw; f < NFRAG; f += GW) {
                const int rb = f >> 3;
                const int cb = f & 7;
                floatx4 accG = {0.f, 0.f, 0.f, 0.f};
#pragma unroll
                for (int kc = 0; kc < 4; ++kc) {
                    const float4* px = (const float4*)&x[(size_t)(rb * 16 + row16) * 128 +
                                                         kc * 32 + kq * 8];
                    float4 v0 = px[0];
                    float4 v1 = px[1];
                    float vals[8] = {v0.x, v0.y, v0.z, v0.w, v1.x, v1.y, v1.z, v1.w};
                    union { unsigned int i[4]; bf16x8 v; } Ha, La;
#pragma unroll
                    for (int j = 0; j < 4; ++j)
                        split2(vals[2 * j], vals[2 * j + 1], Ha.i[j], La.i[j]);
                    bf16x8 bHv = *(const bf16x8*)(wbH + ((size_t)cb * 4 + kc) * 512 +
                                                  lane * 8);
                    bf16x8 bLv = *(const bf16x8*)(wbL + ((size_t)cb * 4 + kc) * 512 +
                                                  lane * 8);
                    accG = __builtin_amdgcn_mfma_f32_16x16x32_bf16(Ha.v, bHv, accG, 0, 0, 0);
                    accG = __builtin_amdgcn_mfma_f32_16x16x32_bf16(Ha.v, bLv, accG, 0, 0, 0);
                    accG = __builtin_amdgcn_mfma_f32_16x16x32_bf16(La.v, bHv, accG, 0, 0, 0);
                }
                const int quad = lane >> 4;
                const int c = cb * 16 + (lane & 15);
#pragma unroll
                for (int rr = 0; rr < 4; ++rr)
                    tA[(size_t)(rb * 16 + quad * 4 + rr) * 128 + c] = accG[rr];
            }
        }
    }
    __threadfence();
    grid.sync();

    // ---- phases 4-7: spmm layers (R8 bodies, grid-stride)
#define RES_ 0
#define RIN_ rA
#define BIAS_ b0
#define GAM_ g0
#define BET_ be0
    SPMM_MID(tA, wbH + (size_t)1 * 16384, wbL + (size_t)1 * 16384,
             wbH + (size_t)4 * 16384, wbL + (size_t)4 * 16384, tB, rB)
#undef RES_
#undef RIN_
#undef BIAS_
#undef GAM_
#undef BET_
    __threadfence();
    grid.sync();

#define RES_ 1
#define RIN_ rB
#define BIAS_ (bh + 0 * HID)
#define GAM_ (gh + 0 * HID)
#define BET_ (beh + 0 * HID)
    SPMM_MID(tB, wbH + (size_t)2 * 16384, wbL + (size_t)2 * 16384,
             wbH + (size_t)5 * 16384, wbL + (size_t)5 * 16384, tA, rA)
#undef RES_
#undef RIN_
#undef BIAS_
#undef GAM_
#undef BET_
    __threadfence();
    grid.sync();

#define RES_ 1
#define RIN_ rA
#define BIAS_ (bh + 1 * HID)
#define GAM_ (gh + 1 * HID)
#define BET_ (beh + 1 * HID)
    SPMM_MID(tA, wbH + (size_t)3 * 16384, wbL + (size_t)3 * 16384,
             wbH + (size_t)6 * 16384, wbL + (size_t)6 * 16384, tB, rB)
#undef RES_
#undef RIN_
#undef BIAS_
#undef GAM_
#undef BET_
    __threadfence();
    grid.sync();

#define RES_ 1
#define RIN_ rB
#define BIAS_ (bh + 2 * HID)
#define GAM_ (gh + 2 * HID)
#define BET_ (beh + 2 * HID)
    SPMM_LAST(tB)
#undef RES_
#undef RIN_
#undef BIAS_
#undef GAM_
#undef BET_
    __threadfence();
    grid.sync();

    // ---- phase 8: MLP head (blocks 0..7: 8 graphs x 128 features each)
    if (bid < 8) {
        const int g2 = (bid << 3) + (tid >> 7);
        const int j = tid & 127;
        float a = mb1[j];
#pragma unroll 8
        for (int k = 0; k < 128; ++k) a += pooled[g2 * 128 + k] * mW1[k * 128 + j];
        shZ[tid] = fmaxf(a, 0.f);
        __syncthreads();
        if (j < NCLASS) {
            float o2 = mb2[j];
            const int zb = tid & ~127;
#pragma unroll 8
            for (int k = 0; k < 128; ++k) o2 += shZ[zb + k] * mW2[k * NCLASS + j];
            out[g2 * NCLASS + j] = o2;
        }
    }
}

// ---------------- launcher ----------------

extern "C" void kernel_launch(void* const* d_in, const int* in_sizes, int n_in,
                              void* d_out, int out_size, void* d_ws, size_t ws_size,
                              hipStream_t stream) {
    const float* x   = (const float*)d_in[0];
    const int*   ei  = (const int*)d_in[1];
    const int* batch = (const int*)d_in[2];
    const float* W0  = (const float*)d_in[3];
    const float* b0  = (const float*)d_in[4];
    const float* g0  = (const float*)d_in[5];
    const float* be0 = (const float*)d_in[6];
    const float* Wh  = (const float*)d_in[7];
    const float* bh  = (const float*)d_in[8];
    const float* gh  = (const float*)d_in[9];
    const float* beh = (const float*)d_in[10];
    const float* Rh  = (const float*)d_in[11];
    const float* mW1 = (const float*)d_in[12];
    const float* mb1 = (const float*)d_in[13];
    const float* mW2 = (const float*)d_in[14];
    const float* mb2 = (const float*)d_in[15];
    float* out = (float*)d_out;

    char* ws = (char*)d_ws;
    size_t off = 0;
    auto alloc = [&](size_t bytes) -> void* {
        void* p = ws + off;
        off += (bytes + 255) & ~(size_t)255;
        return p;
    };
    int*   deg8   = (int*)alloc((size_t)NREP * NN * 4);
    float* pooled = (float*)alloc((size_t)NGRAPH * HID * 4);
    int*   degT   = (int*)alloc((size_t)NN * 4);
    int*   rowptr = (int*)alloc((size_t)NN * 4);
    int*   cur    = (int*)alloc((size_t)NN * 4);
    int*   cursor = (int*)alloc(256);
    int*   meta   = (int*)alloc((size_t)NEPAD * 4);
    float* tA     = (float*)alloc((size_t)NN * HID * 4);
    float* tB     = (float*)alloc((size_t)NN * HID * 4);
    float* rA     = (float*)alloc((size_t)NN * HID * 4);
    float* rB     = (float*)alloc((size_t)NN * HID * 4);
    unsigned short* wbH = (unsigned short*)alloc((size_t)7 * 16384 * 2);
    unsigned short* wbL = (unsigned short*)alloc((size_t)7 * 16384 * 2);

    int maxB = 0;
    hipOccupancyMaxActiveBlocksPerMultiprocessor(&maxB, k_mega, 1024, 0);
    if (maxB < 1) maxB = 1;
    int G = maxB * 256;
    if (G > 512) G = 512;

    void* args[] = {
        (void*)&x,   (void*)&ei,  (void*)&batch,
        (void*)&W0,  (void*)&b0,  (void*)&g0,  (void*)&be0,
        (void*)&Wh,  (void*)&bh,  (void*)&gh,  (void*)&beh,
        (void*)&Rh,  (void*)&mW1, (void*)&mb1, (void*)&mW2, (void*)&mb2,
        (void*)&out, (void*)&deg8, (void*)&degT, (void*)&rowptr,
        (void*)&cur, (void*)&cursor, (void*)&meta,
        (void*)&tA,  (void*)&tB,  (void*)&rA,  (void*)&rB,
        (void*)&wbH, (void*)&wbL, (void*)&pooled};
    hipLaunchCooperativeKernel(k_mega, dim3(G), dim3(1024), args, 0, stream);
}

// Round 10
// 436.219 us; speedup vs baseline: 3.4075x; 3.4075x over previous
//
#include <hip/hip_runtime.h>
#include <cstdint>
#include <cstddef>

#define NN 50000
#define NE 800000
#define NEPAD (NE + 3 * NN)   // CSR rows padded to multiple of 4
#define HID 128
#define NGRAPH 64
#define NCLASS 10
#define LHID 3
#define NREP 8                // deg counter replicas

// 16-row fragment blocks: 50000/16 = 3125 exact; GEMM covers 782*4 = 3128
#define ROWBLK 3125
#define ROWBLK_PAD 3128
#define GEMM_GRID 782         // 64-row tiles
#define FILL_GRID 3125        // 800000 / 256
#define FRONT_DEG 3125        // deg blocks (FIRST: they are the long pole)
#define FRONT_B 56            // convB blocks (8 x 7 mats)
#define FRONT_GRID (FRONT_DEG + FRONT_B)

// 1/sqrt(1+1e-5), computed in double, rounded to f32
static constexpr float BN_INV = 0.9999950000374996f;

typedef __attribute__((ext_vector_type(8))) __bf16 bf16x8;
typedef __attribute__((ext_vector_type(4))) float floatx4;

// ---------------- bf16 split helpers ----------------

__device__ __forceinline__ unsigned int f32_to_bf16_rne(float f) {
    unsigned int u = __float_as_uint(f);
    return (u + 0x7FFFu + ((u >> 16) & 1u)) >> 16;
}
__device__ __forceinline__ float bf16_to_f32(unsigned int h) {
    return __uint_as_float(h << 16);
}
__device__ __forceinline__ void split2(float a, float b, unsigned int& hi,
                                       unsigned int& lo) {
    unsigned int h0 = f32_to_bf16_rne(a), h1 = f32_to_bf16_rne(b);
    unsigned int l0 = f32_to_bf16_rne(a - bf16_to_f32(h0));
    unsigned int l1 = f32_to_bf16_rne(b - bf16_to_f32(h1));
    hi = h0 | (h1 << 16);
    lo = l0 | (l1 << 16);
}

// ---------------- front: deg (R6 form, proven) + convB ---------------------

__global__ void k_front(const float* __restrict__ W0, const float* __restrict__ Wh,
                        const float* __restrict__ Rh, unsigned short* __restrict__ bH,
                        unsigned short* __restrict__ bL,
                        const int* __restrict__ ei, int* __restrict__ deg8,
                        int* __restrict__ eslot) {
    const int b = blockIdx.x;
    const int tid = threadIdx.x;
    if (b < FRONT_DEG) {
        // deg histogram with 8x replicated counters (contention /8) + slot record
        int e = b * 256 + tid;                  // < 800000 exact
        int d = ei[NE + e];
        int rep = e & (NREP - 1);
        eslot[e] = atomicAdd(&deg8[rep * NN + d], 1);
    } else {
        // convB: W [k][n] f32 -> swizzled fragments; 7 matrices.
        int cb = b - FRONT_DEG;
        int mat = cb >> 3;
        const float* src = (mat == 0) ? W0
                         : (mat <= 3) ? (Wh + (size_t)(mat - 1) * 16384)
                                      : (Rh + (size_t)(mat - 4) * 16384);
        int u = (cb & 7) * 256 + tid;  // 0..2047
        int lane = u & 63;
        int blk = u >> 6;
        int kblk = blk & 3;
        int nb = blk >> 2;
        int n = nb * 16 + (lane & 15);
        int k = kblk * 32 + (lane >> 4) * 8;
        union { unsigned int i[4]; uint4 v; } H, L;
#pragma unroll
        for (int j = 0; j < 4; ++j) {
            float a = src[(size_t)(k + 2 * j) * 128 + n];
            float c = src[(size_t)(k + 2 * j + 1) * 128 + n];
            split2(a, c, H.i[j], L.i[j]);
        }
        size_t base = (size_t)mat * 16384 + (size_t)u * 8;
        *(uint4*)&bH[base] = H.v;
        *(uint4*)&bL[base] = L.v;
    }
}

// ---------------- scan1: replica reduce + per-rep offsets + bsum -----------
// dinv dropped: gather recomputes rsqrtf(deg+1) (bit-identical instruction).

__global__ void k_scan1(const int* __restrict__ deg8, int* __restrict__ degT,
                        int* __restrict__ degOff, int* __restrict__ bsum) {
    __shared__ int s[256];
    int i = blockIdx.x * 256 + threadIdx.x;
    int dsum = 0;
    if (i < NN) {
        int off[NREP];
#pragma unroll
        for (int r = 0; r < NREP; ++r) {
            off[r] = dsum;
            dsum += deg8[r * NN + i];
        }
#pragma unroll
        for (int r = 0; r < NREP; ++r) degOff[i * NREP + r] = off[r];
        degT[i] = dsum;
    }
    s[threadIdx.x] = (dsum + 3) & ~3;
    __syncthreads();
    for (int o = 128; o > 0; o >>= 1) {
        if (threadIdx.x < o) s[threadIdx.x] += s[threadIdx.x + o];
        __syncthreads();
    }
    if (threadIdx.x == 0) bsum[blockIdx.x] = s[0];
}

// ---------------- scan3: rowptr (inlines scan2) + CSR pad sentinel ---------

__global__ void k_scan3(const int* __restrict__ degT, const int* __restrict__ bsum,
                        int* __restrict__ rowptr, int* __restrict__ meta) {
    __shared__ int s[256];
    __shared__ int offS;
    const int bid = blockIdx.x;
    s[threadIdx.x] = (threadIdx.x < bid) ? bsum[threadIdx.x] : 0;
    __syncthreads();
    for (int o = 128; o > 0; o >>= 1) {
        if (threadIdx.x < o) s[threadIdx.x] += s[threadIdx.x + o];
        __syncthreads();
    }
    if (threadIdx.x == 0) offS = s[0];
    __syncthreads();
    const int off = offS;
    __syncthreads();
    int i = bid * 256 + threadIdx.x;
    int d = (i < NN) ? degT[i] : 0;
    int v = (d + 3) & ~3;
    s[threadIdx.x] = v;
    __syncthreads();
    for (int o = 1; o < 256; o <<= 1) {
        int tv = (threadIdx.x >= o) ? s[threadIdx.x - o] : 0;
        __syncthreads();
        s[threadIdx.x] += tv;
        __syncthreads();
    }
    if (i < NN) {
        int rp = off + s[threadIdx.x] - v;  // exclusive
        rowptr[i] = rp;
        // pad slots (<=3 per row): sign bit -> weight 0 in gather, row 0
        for (int p = rp + d; p < rp + v; ++p) meta[p] = (int)0x80000000u;
    }
}

// ---------------- MFMA GEMM0: C1 = X @ B1, split-bf16, LDS-free ------------
// XA: A fragments built from f32 x on the fly (split2 in reg). FILL adds
// CSR-fill blocks past GEMM_GRID (R6's eslot/degOff slotting -- no atomics),
// writing packed meta = src | degT[src]<<17 (ONE scatter/edge; the gather
// recomputes w = rsqrtf(deg+1), bit-identical to the old dinv[src]).

template <int NB, bool FILL, bool XA>
__global__ __launch_bounds__(256, 3) void k_gemm_mfma(
    const float* __restrict__ X,
    const unsigned short* __restrict__ Ahi, const unsigned short* __restrict__ Alo,
    const unsigned short* __restrict__ B1hi, const unsigned short* __restrict__ B1lo,
    const unsigned short* __restrict__ B2hi, const unsigned short* __restrict__ B2lo,
    float* __restrict__ C1, float* __restrict__ C2,
    const int* __restrict__ ei, const int* __restrict__ rowptr,
    const int* __restrict__ eslot, const int* __restrict__ degOff,
    const int* __restrict__ degT, int* __restrict__ meta) {
    if (FILL && blockIdx.x >= GEMM_GRID) {
        int e = (blockIdx.x - GEMM_GRID) * 256 + threadIdx.x;  // < 800000 exact
        int s = ei[e];
        int d = ei[NE + e];
        int rep = e & (NREP - 1);
        int p = rowptr[d] + degOff[d * NREP + rep] + eslot[e];
        meta[p] = s | (degT[s] << 17);
        return;
    }
    const int tid = threadIdx.x;
    const int wave = tid >> 6;
    const int lane = tid & 63;
    const int wm = wave & 1;
    const int wn = wave >> 1;
    const int rb0 = blockIdx.x * 4;         // first 16-row block

    floatx4 acc1[2][4], acc2[2][4];
    floatx4 zero = {0.f, 0.f, 0.f, 0.f};
#pragma unroll
    for (int i = 0; i < 2; ++i)
#pragma unroll
        for (int j = 0; j < 4; ++j) { acc1[i][j] = zero; if (NB == 2) acc2[i][j] = zero; }

#pragma unroll
    for (int kc = 0; kc < 4; ++kc) {
        bf16x8 aH[2], aL[2], bH[4], bL[4];
        if (XA) {
#pragma unroll
            for (int t = 0; t < 2; ++t) {
                int m = (rb0 + wm * 2 + t) * 16 + (lane & 15);
                if (m >= NN) m = NN - 1;   // pad rows: read safe, never written
                const float4* p =
                    (const float4*)&X[(size_t)m * 128 + kc * 32 + (lane >> 4) * 8];
                float4 v0 = p[0];
                float4 v1 = p[1];
                float vals[8] = {v0.x, v0.y, v0.z, v0.w, v1.x, v1.y, v1.z, v1.w};
                union { unsigned int i[4]; bf16x8 v; } H, L;
#pragma unroll
                for (int j = 0; j < 4; ++j)
                    split2(vals[2 * j], vals[2 * j + 1], H.i[j], L.i[j]);
                aH[t] = H.v;
                aL[t] = L.v;
            }
        } else {
#pragma unroll
            for (int t = 0; t < 2; ++t) {
                size_t u = ((size_t)(rb0 + wm * 2 + t) * 4 + kc) * 512 + lane * 8;
                aH[t] = *(const bf16x8*)(Ahi + u);
                aL[t] = *(const bf16x8*)(Alo + u);
            }
        }
#pragma unroll
        for (int t = 0; t < 4; ++t)
            bH[t] = *(const bf16x8*)(B1hi + ((size_t)(wn * 4 + t) * 4 + kc) * 512 +
                                     lane * 8);
#pragma unroll
        for (int tm = 0; tm < 2; ++tm)
#pragma unroll
            for (int tn = 0; tn < 4; ++tn)
                acc1[tm][tn] = __builtin_amdgcn_mfma_f32_16x16x32_bf16(
                    aH[tm], bH[tn], acc1[tm][tn], 0, 0, 0);
#pragma unroll
        for (int t = 0; t < 4; ++t)
            bL[t] = *(const bf16x8*)(B1lo + ((size_t)(wn * 4 + t) * 4 + kc) * 512 +
                                     lane * 8);
#pragma unroll
        for (int tm = 0; tm < 2; ++tm)
#pragma unroll
            for (int tn = 0; tn < 4; ++tn)
                acc1[tm][tn] = __builtin_amdgcn_mfma_f32_16x16x32_bf16(
                    aH[tm], bL[tn], acc1[tm][tn], 0, 0, 0);
#pragma unroll
        for (int tm = 0; tm < 2; ++tm)
#pragma unroll
            for (int tn = 0; tn < 4; ++tn)
                acc1[tm][tn] = __builtin_amdgcn_mfma_f32_16x16x32_bf16(
                    aL[tm], bH[tn], acc1[tm][tn], 0, 0, 0);
        if (NB == 2) {
#pragma unroll
            for (int t = 0; t < 4; ++t)
                bH[t] = *(const bf16x8*)(B2hi + ((size_t)(wn * 4 + t) * 4 + kc) * 512 +
                                         lane * 8);
#pragma unroll
            for (int tm = 0; tm < 2; ++tm)
#pragma unroll
                for (int tn = 0; tn < 4; ++tn)
                    acc2[tm][tn] = __builtin_amdgcn_mfma_f32_16x16x32_bf16(
                        aH[tm], bH[tn], acc2[tm][tn], 0, 0, 0);
#pragma unroll
            for (int tm = 0; tm < 2; ++tm)
#pragma unroll
                for (int tn = 0; tn < 4; ++tn)
                    acc2[tm][tn] = __builtin_amdgcn_mfma_f32_16x16x32_bf16(
                        aL[tm], bH[tn], acc2[tm][tn], 0, 0, 0);
#pragma unroll
            for (int t = 0; t < 4; ++t)
                bL[t] = *(const bf16x8*)(B2lo + ((size_t)(wn * 4 + t) * 4 + kc) * 512 +
                                         lane * 8);
#pragma unroll
            for (int tm = 0; tm < 2; ++tm)
#pragma unroll
                for (int tn = 0; tn < 4; ++tn)
                    acc2[tm][tn] = __builtin_amdgcn_mfma_f32_16x16x32_bf16(
                        aH[tm], bL[tn], acc2[tm][tn], 0, 0, 0);
        }
    }

    // epilogue: C/D layout col = lane&15, row = (lane>>4)*4 + r
    const int quad = lane >> 4;
    const int col0 = lane & 15;
    const int rowBase = blockIdx.x * 64 + wm * 32;
#pragma unroll
    for (int tm = 0; tm < 2; ++tm) {
#pragma unroll
        for (int tn = 0; tn < 4; ++tn) {
            int c = wn * 64 + tn * 16 + col0;
#pragma unroll
            for (int r = 0; r < 4; ++r) {
                int row = rowBase + tm * 16 + quad * 4 + r;
                if (row < NN) {
                    C1[(size_t)row * 128 + c] = acc1[tm][tn][r];
                    if (NB == 2) C2[(size_t)row * 128 + c] = acc2[tm][tn][r];
                }
            }
        }
    }
}

// ---------------- SpMM + fused next-layer GEMM (R6 structure, R8 gather) ---
// Gather: 1 node/wave, 16 waves/block, 512 B row bursts, scalarized packed
// meta (ONE s_load_dwordx4 per 4 edges; w = rsqrtf(deg+1) recomputed --
// bit-identical to dinv). At the quadruple-confirmed ~3.7 TB/s random-burst
// fabric floor. Fused GEMM: unit-swizzled LDS staging (0 bank conflicts),
// B-fragment loads issued before the barrier.

template <bool RES, bool LAST>
__global__ __launch_bounds__(1024, 8) void k_spmm(
    const float* __restrict__ t, const float* __restrict__ r,
    const int* __restrict__ rowptr, const int* __restrict__ degT,
    const int* __restrict__ meta,
    const float* __restrict__ bias, const float* __restrict__ gamma,
    const float* __restrict__ beta,
    const unsigned short* __restrict__ w1H, const unsigned short* __restrict__ w1L,
    const unsigned short* __restrict__ w2H, const unsigned short* __restrict__ w2L,
    float* __restrict__ tOut, float* __restrict__ rOut,
    const int* __restrict__ batch, float* __restrict__ pooled) {
    __shared__ unsigned short shU[2][16][16][8];  // non-LAST: [H/L][unit][row^u][8]
    __shared__ float shP[16][128];                // LAST only: per-wave values
    const int tid = threadIdx.x;
    const int lane = tid & 63;
    const int h = lane >> 5;                 // row-in-pair, 0..1
    const int f4 = lane & 31;                // feature quad, 0..31
    const int wv = __builtin_amdgcn_readfirstlane(tid >> 6);  // node in block
    const int node = blockIdx.x * 16 + wv;   // grid = NN/16 exact

    const int start = __builtin_amdgcn_readfirstlane(rowptr[node]);
    const int dg = __builtin_amdgcn_readfirstlane(degT[node]);
    const int cnt4 = (dg + 3) >> 2;

    float4 acc = {0.f, 0.f, 0.f, 0.f};
#pragma unroll 4
    for (int q = 0; q < cnt4; ++q) {
        // wave-uniform address -> one scalar dwordx4 (K$) per 4 edges
        const int4 m4 = *(const int4*)(meta + start + q * 4);
        const unsigned int mvA = (unsigned int)(h ? m4.y : m4.x);
        const unsigned int mvB = (unsigned int)(h ? m4.w : m4.z);
        const int rowA = (int)(mvA & 0x1FFFFu);
        const int rowB = (int)(mvB & 0x1FFFFu);
        float wA = rsqrtf((float)((mvA >> 17) + 1u));
        float wB = rsqrtf((float)((mvB >> 17) + 1u));
        wA = ((int)mvA < 0) ? 0.f : wA;
        wB = ((int)mvB < 0) ? 0.f : wB;
        const float4 vA = *(const float4*)&t[(size_t)rowA * 128 + f4 * 4];
        const float4 vB = *(const float4*)&t[(size_t)rowB * 128 + f4 * 4];
        acc.x = fmaf(wA, vA.x, acc.x); acc.y = fmaf(wA, vA.y, acc.y);
        acc.z = fmaf(wA, vA.z, acc.z); acc.w = fmaf(wA, vA.w, acc.w);
        acc.x = fmaf(wB, vB.x, acc.x); acc.y = fmaf(wB, vB.y, acc.y);
        acc.z = fmaf(wB, vB.z, acc.z); acc.w = fmaf(wB, vB.w, acc.w);
    }
    // combine the two half-wave partials (lane ^ 32)
    acc.x += __shfl_xor(acc.x, 32);
    acc.y += __shfl_xor(acc.y, 32);
    acc.z += __shfl_xor(acc.z, 32);
    acc.w += __shfl_xor(acc.w, 32);

    const int f0 = f4 * 4;
    float4 o;
    if (h == 0) {
        const float di = rsqrtf((float)(dg + 1));
        const float dii = di * di;
        const float4 tv = *(const float4*)&t[(size_t)node * 128 + f0];
        const float4 bv = *(const float4*)&bias[f0];
        const float4 gv = *(const float4*)&gamma[f0];
        const float4 ev = *(const float4*)&beta[f0];
        float4 cc;
        cc.x = di * acc.x + dii * tv.x + bv.x;
        cc.y = di * acc.y + dii * tv.y + bv.y;
        cc.z = di * acc.z + dii * tv.z + bv.z;
        cc.w = di * acc.w + dii * tv.w + bv.w;
        if (RES) {
            const float4 rv = *(const float4*)&r[(size_t)node * 128 + f0];
            cc.x += rv.x; cc.y += rv.y; cc.z += rv.z; cc.w += rv.w;
        }
        o.x = fmaxf(cc.x * (BN_INV * gv.x) + ev.x, 0.f);
        o.y = fmaxf(cc.y * (BN_INV * gv.y) + ev.y, 0.f);
        o.z = fmaxf(cc.z * (BN_INV * gv.z) + ev.z, 0.f);
        o.w = fmaxf(cc.w * (BN_INV * gv.w) + ev.w, 0.f);
    }

    if (LAST) {
        bool uni = (batch[blockIdx.x * 16] == batch[blockIdx.x * 16 + 15]);
        if (uni) {
            if (h == 0) *(float4*)&shP[wv][f0] = o;
            __syncthreads();
            if (wv == 0) {
                float a = shP[0][2 * lane], b = shP[0][2 * lane + 1];
#pragma unroll
                for (int w = 1; w < 16; ++w) {
                    a = fmaxf(a, shP[w][2 * lane]);
                    b = fmaxf(b, shP[w][2 * lane + 1]);
                }
                int g = batch[blockIdx.x * 16];
                atomicMax((unsigned int*)&pooled[g * 128 + 2 * lane],
                          __float_as_uint(a));
                atomicMax((unsigned int*)&pooled[g * 128 + 2 * lane + 1],
                          __float_as_uint(b));
            }
        } else if (h == 0) {
            int g = batch[node];
            atomicMax((unsigned int*)&pooled[g * 128 + f0], __float_as_uint(o.x));
            atomicMax((unsigned int*)&pooled[g * 128 + f0 + 1], __float_as_uint(o.y));
            atomicMax((unsigned int*)&pooled[g * 128 + f0 + 2], __float_as_uint(o.z));
            atomicMax((unsigned int*)&pooled[g * 128 + f0 + 3], __float_as_uint(o.w));
        }
        return;
    }

    // stage h into unit-swizzled LDS: features f4*4..+3 live in unit f4>>1
    if (h == 0) {
        unsigned int H0, L0, H1, L1;
        split2(o.x, o.y, H0, L0);
        split2(o.z, o.w, H1, L1);
        const int u = f4 >> 1;
        const int ro = wv ^ u;
        const int so = (f4 & 1) * 4;
        uint2 Hv; Hv.x = H0; Hv.y = H1;
        uint2 Lv; Lv.x = L0; Lv.y = L1;
        *(uint2*)&shU[0][u][ro][so] = Hv;
        *(uint2*)&shU[1][u][ro][so] = Lv;
    }

    // issue B-fragment loads NOW: their drain at the barrier overlaps the
    // other waves' gather imbalance instead of serializing after it.
    const int w = tid >> 6;
    const int mat = w >> 3;                  // 0: W -> tOut, 1: R -> rOut
    const int nb = w & 7;                    // 16-col tile
    const unsigned short* BH = mat ? w2H : w1H;
    const unsigned short* BL = mat ? w2L : w1L;
    bf16x8 bHr[4], bLr[4];
#pragma unroll
    for (int kc = 0; kc < 4; ++kc) {
        bHr[kc] = *(const bf16x8*)(BH + ((size_t)nb * 4 + kc) * 512 + lane * 8);
        bLr[kc] = *(const bf16x8*)(BL + ((size_t)nb * 4 + kc) * 512 + lane * 8);
    }
    __syncthreads();

    // fused next-layer linear: A-fragment lane l: row = l&15, unit = kc*4+(l>>4)
    float* outp = mat ? rOut : tOut;
    floatx4 accG = {0.f, 0.f, 0.f, 0.f};
#pragma unroll
    for (int kc = 0; kc < 4; ++kc) {
        const int uu = kc * 4 + (lane >> 4);
        const int rr = (lane & 15) ^ uu;
        bf16x8 aH = *(const bf16x8*)&shU[0][uu][rr][0];
        bf16x8 aL = *(const bf16x8*)&shU[1][uu][rr][0];
        accG = __builtin_amdgcn_mfma_f32_16x16x32_bf16(aH, bHr[kc], accG, 0, 0, 0);
        accG = __builtin_amdgcn_mfma_f32_16x16x32_bf16(aH, bLr[kc], accG, 0, 0, 0);
        accG = __builtin_amdgcn_mfma_f32_16x16x32_bf16(aL, bHr[kc], accG, 0, 0, 0);
    }
    // C/D layout: col = lane&15, row = (lane>>4)*4 + r
    const int quad = lane >> 4;
    const int c0 = nb * 16 + (lane & 15);
    const int row0 = blockIdx.x * 16 + quad * 4;
#pragma unroll
    for (int rr2 = 0; rr2 < 4; ++rr2)
        outp[(size_t)(row0 + rr2) * 128 + c0] = accG[rr2];
}

// ---------------- MLP head (64 parallel blocks) ----------------

__global__ void k_head(const float* __restrict__ pooled, const float* __restrict__ mW1,
                       const float* __restrict__ mb1, const float* __restrict__ mW2,
                       const float* __restrict__ mb2, float* __restrict__ out) {
    __shared__ float p[128];
    __shared__ float z[128];
    int g = blockIdx.x;
    int j = threadIdx.x;  // 128 threads
    p[j] = pooled[g * 128 + j];
    __syncthreads();
    float a = mb1[j];
#pragma unroll 8
    for (int k = 0; k < 128; ++k) a += p[k] * mW1[k * 128 + j];
    z[j] = fmaxf(a, 0.f);
    __syncthreads();
    if (j < NCLASS) {
        float o = mb2[j];
#pragma unroll 8
        for (int k = 0; k < 128; ++k) o += z[k] * mW2[k * NCLASS + j];
        out[g * NCLASS + j] = o;
    }
}

// ---------------- launcher ----------------

extern "C" void kernel_launch(void* const* d_in, const int* in_sizes, int n_in,
                              void* d_out, int out_size, void* d_ws, size_t ws_size,
                              hipStream_t stream) {
    const float* x   = (const float*)d_in[0];
    const int*   ei  = (const int*)d_in[1];
    const int* batch = (const int*)d_in[2];
    const float* W0  = (const float*)d_in[3];
    const float* b0  = (const float*)d_in[4];
    const float* g0  = (const float*)d_in[5];
    const float* be0 = (const float*)d_in[6];
    const float* Wh  = (const float*)d_in[7];
    const float* bh  = (const float*)d_in[8];
    const float* gh  = (const float*)d_in[9];
    const float* beh = (const float*)d_in[10];
    const float* Rh  = (const float*)d_in[11];
    const float* mW1 = (const float*)d_in[12];
    const float* mb1 = (const float*)d_in[13];
    const float* mW2 = (const float*)d_in[14];
    const float* mb2 = (const float*)d_in[15];
    float* out = (float*)d_out;

    char* ws = (char*)d_ws;
    size_t off = 0;
    auto alloc = [&](size_t bytes) -> void* {
        void* p = ws + off;
        off += (bytes + 255) & ~(size_t)255;
        return p;
    };
    // deg8 + pooled adjacent -> single memset covers both
    int*   deg8   = (int*)alloc((size_t)NREP * NN * 4);
    float* pooled = (float*)alloc((size_t)NGRAPH * HID * 4);
    size_t zspan = (size_t)((char*)pooled - (char*)deg8) + (size_t)NGRAPH * HID * 4;
    int*   degT   = (int*)alloc((size_t)NN * 4);
    int*   degOff = (int*)alloc((size_t)NN * NREP * 4);
    int*   rowptr = (int*)alloc((size_t)NN * 4);
    int*   bsum   = (int*)alloc(256 * 4);
    int*   eslot  = (int*)alloc((size_t)NE * 4);
    int*   meta   = (int*)alloc((size_t)NEPAD * 4);
    // ping-pong f32 activation / residual buffers
    float* tA     = (float*)alloc((size_t)NN * HID * 4);
    float* tB     = (float*)alloc((size_t)NN * HID * 4);
    float* rA     = (float*)alloc((size_t)NN * HID * 4);
    float* rB     = (float*)alloc((size_t)NN * HID * 4);
    // swizzled weights, 7 matrices (0:W0, 1-3:Wh, 4-6:Rh)
    unsigned short* bH = (unsigned short*)alloc((size_t)7 * 16384 * 2);
    unsigned short* bL = (unsigned short*)alloc((size_t)7 * 16384 * 2);

    hipMemsetAsync(deg8, 0, zspan, stream);

    k_front<<<FRONT_GRID, 256, 0, stream>>>(W0, Wh, Rh, bH, bL, ei, deg8, eslot);
    k_scan1<<<(NN + 255) / 256, 256, 0, stream>>>(deg8, degT, degOff, bsum);
    k_scan3<<<(NN + 255) / 256, 256, 0, stream>>>(degT, bsum, rowptr, meta);

    // GEMM0 (x read direct, split in-register) fused with CSR fill -> tA
    k_gemm_mfma<1, true, true><<<GEMM_GRID + FILL_GRID, 256, 0, stream>>>(
        x, nullptr, nullptr, bH, bL, nullptr, nullptr, tA, nullptr,
        ei, rowptr, eslot, degOff, degT, meta);

    const int spmmGrid = NN / 16;  // 3125 blocks x 1024 threads

    // spmm0: conv0 epilogue + fused GEMM (Wh0, Rh0) -> tB, rB
    k_spmm<false, false><<<spmmGrid, 1024, 0, stream>>>(
        tA, nullptr, rowptr, degT, meta, b0, g0, be0,
        bH + (size_t)1 * 16384, bL + (size_t)1 * 16384,
        bH + (size_t)4 * 16384, bL + (size_t)4 * 16384,
        tB, rB, nullptr, nullptr);

    // spmm1: layer1 + fused GEMM (Wh1, Rh1) -> tA, rA
    k_spmm<true, false><<<spmmGrid, 1024, 0, stream>>>(
        tB, rB, rowptr, degT, meta, bh + 0 * HID, gh + 0 * HID,
        beh + 0 * HID,
        bH + (size_t)2 * 16384, bL + (size_t)2 * 16384,
        bH + (size_t)5 * 16384, bL + (size_t)5 * 16384,
        tA, rA, nullptr, nullptr);

    // spmm2: layer2 + fused GEMM (Wh2, Rh2) -> tB, rB
    k_spmm<true, false><<<spmmGrid, 1024, 0, stream>>>(
        tA, rA, rowptr, degT, meta, bh + 1 * HID, gh + 1 * HID,
        beh + 1 * HID,
        bH + (size_t)3 * 16384, bL + (size_t)3 * 16384,
        bH + (size_t)6 * 16384, bL + (size_t)6 * 16384,
        tB, rB, nullptr, nullptr);

    // spmm3 (LAST): layer3 + fused max-pool
    k_spmm<true, true><<<spmmGrid, 1024, 0, stream>>>(
        tB, rB, rowptr, degT, meta, bh + 2 * HID, gh + 2 * HID,
        beh + 2 * HID,
        nullptr, nullptr, nullptr, nullptr,
        nullptr, nullptr, batch, pooled);

    k_head<<<NGRAPH, 128, 0, stream>>>(pooled, mW1, mb1, mW2, mb2, out);
}